// Round 4
// baseline (270.767 us; speedup 1.0000x reference)
//
#include <hip/hip_runtime.h>
#include <math.h>

#define V 100000
#define D 256
#define B 32
#define N 128
#define K 100
#define NPOS (B * N)             // 4096
#define NPAIR (NPOS * (K + 1))   // 413,696 (noise pairs + target pairs)
#define BIN_ROWS 64
#define NBIN ((V + BIN_ROWS - 1) / BIN_ROWS)   // 1563
#define CAP 512                  // pairs/bin capacity (mean 265, sigma ~16 -> +15 sigma)
#define NORM_TERM 11.512925f
#define LOG_K 4.605170186f       // log(100)

typedef float f32x4 __attribute__((ext_vector_type(4)));
typedef unsigned short u16;

// softplus(x) = max(x,0) + log1p(exp(-|x|)) — overflow-safe, fast intrinsics
__device__ __forceinline__ float softplus(float x) {
    return fmaxf(x, 0.f) + __logf(1.f + __expf(-fabsf(x)));
}
__device__ __forceinline__ u16 f32_to_bf16(float x) {   // RNE
    unsigned u = __float_as_uint(x);
    u += 0x7FFFu + ((u >> 16) & 1u);
    return (u16)(u >> 16);
}
__device__ __forceinline__ float bf16_to_f32(u16 h) {
    return __uint_as_float(((unsigned)h) << 16);
}

// ---------- Pass 1: bin all (pos,row) pairs by row block ----------
// rec = row<<13 | pos<<1 | is_target   (17+12+1 = 30 bits)
__global__ __launch_bounds__(256) void scatter_kernel(
    const int* __restrict__ target, const int* __restrict__ noise,
    int* __restrict__ cursor, unsigned* __restrict__ buf)
{
    const int p = blockIdx.x * 256 + threadIdx.x;
    if (p >= NPAIR) return;
    int row, pos; unsigned flag;
    if (p < NPOS * K) { pos = p / K; row = noise[p]; flag = 0u; }
    else              { pos = p - NPOS * K; row = target[pos]; flag = 1u; }
    const int bin  = row >> 6;                       // BIN_ROWS = 64
    const int slot = atomicAdd(&cursor[bin], 1);
    if (slot < CAP)
        buf[(size_t)bin * CAP + slot] =
            ((unsigned)row << 13) | ((unsigned)pos << 1) | flag;
}

// ---------- Pass 2: one block per bin ----------
// Stream the bin's 64-row weight slab (coalesced, nontemporal) into LDS as
// bf16 (32 KB), then process the bin's pairs: 16 lanes per pair, weight from
// LDS, hidden from global (4 MB table, L2/LLC-hot).
__global__ __launch_bounds__(256) void compute_kernel(
    const float* __restrict__ hidden, const float* __restrict__ weight,
    const float* __restrict__ bias, const float* __restrict__ noise_probs,
    const int* __restrict__ cursor, const unsigned* __restrict__ buf,
    float* __restrict__ out)
{
    __shared__ u16   slab[BIN_ROWS * D];   // 32 KB bf16
    __shared__ float sbias[BIN_ROWS];
    __shared__ float slogp[BIN_ROWS];
    __shared__ float wsum[4];

    const int bin = blockIdx.x;
    int cnt = cursor[bin];
    if (cnt <= 0) return;                  // uniform exit, before any barrier
    if (cnt > CAP) cnt = CAP;

    const int tid  = threadIdx.x;
    const int wave = tid >> 6;             // 0..3
    const int lane = tid & 63;
    const int q    = lane >> 4;            // pair slot within wave 0..3
    const int ql   = lane & 15;            // lane within quarter

    const int row0 = bin * BIN_ROWS;
    const int rmax = min(V - row0, BIN_ROWS);

    // stage slab: wave w loads rows w, w+4, ... ; one full 1 KB row per
    // wave-instruction (64 lanes x float4), nontemporal to spare L2 for hidden
    for (int r = wave; r < rmax; r += 4) {
        const f32x4 w4 = __builtin_nontemporal_load(
            (const f32x4*)(weight + (size_t)(row0 + r) * D + lane * 4));
        ushort4 b;
        b.x = f32_to_bf16(w4.x); b.y = f32_to_bf16(w4.y);
        b.z = f32_to_bf16(w4.z); b.w = f32_to_bf16(w4.w);
        *(ushort4*)(slab + r * D + lane * 4) = b;
    }
    if (tid < rmax) {                      // coalesced: rows contiguous in bin
        sbias[tid] = bias[row0 + tid];
        slogp[tid] = __logf(noise_probs[row0 + tid]);
    }
    __syncthreads();

    float loss = 0.f;
    const unsigned* __restrict__ bbuf = buf + (size_t)bin * CAP;
    for (int base = wave * 4; base < cnt; base += 16) {
        const int p = base + q;
        const bool valid = (p < cnt);
        const unsigned rec = valid ? bbuf[p] : 0u;
        const int rloc = (int)((rec >> 13) & (BIN_ROWS - 1));
        const int pos  = (int)((rec >> 1) & (NPOS - 1));

        const float* __restrict__ hp = hidden + (size_t)pos * D + ql * 4;
        const u16*   __restrict__ wp = slab + rloc * D + ql * 4;
        float acc = 0.f;
        #pragma unroll
        for (int i = 0; i < 4; ++i) {
            const f32x4   h4 = *(const f32x4*)(hp + i * 64);
            const ushort4 w4 = *(const ushort4*)(wp + i * 64);
            acc = fmaf(bf16_to_f32(w4.x), h4.x, acc);
            acc = fmaf(bf16_to_f32(w4.y), h4.y, acc);
            acc = fmaf(bf16_to_f32(w4.z), h4.z, acc);
            acc = fmaf(bf16_to_f32(w4.w), h4.w, acc);
        }
        #pragma unroll
        for (int off = 1; off < 16; off <<= 1)   // reduce within quarter
            acc += __shfl_xor(acc, off, 64);

        const float score = acc + sbias[rloc] - NORM_TERM;
        const float contrib = (rec & 1u)
            ? softplus(LOG_K - score)                      // target, label 1
            : softplus(score - slogp[rloc] - LOG_K);       // noise, label 0
        if (valid && ql == 0) loss += contrib;
    }

    // fold the 4 quarters of each wave, then the 4 waves
    loss += __shfl_xor(loss, 16, 64);
    loss += __shfl_xor(loss, 32, 64);
    if (lane == 0) wsum[wave] = loss;
    __syncthreads();
    if (tid == 0)
        atomicAdd(out, (wsum[0] + wsum[1] + wsum[2] + wsum[3])
                       * (1.0f / (float)NPOS));
}

extern "C" void kernel_launch(void* const* d_in, const int* in_sizes, int n_in,
                              void* d_out, int out_size, void* d_ws, size_t ws_size,
                              hipStream_t stream) {
    const int*   target      = (const int*)d_in[0];
    const int*   noise       = (const int*)d_in[1];
    const float* hidden      = (const float*)d_in[2];
    const float* weight      = (const float*)d_in[3];
    const float* bias        = (const float*)d_in[4];
    const float* noise_probs = (const float*)d_in[5];
    float* out = (float*)d_out;

    // workspace: [0, 8K) bin cursors, [8K, 8K+3.2MB) pair records
    int*      cursor = (int*)d_ws;
    unsigned* buf    = (unsigned*)((char*)d_ws + 8192);

    hipMemsetAsync(cursor, 0, NBIN * sizeof(int), stream);
    hipMemsetAsync(out, 0, sizeof(float), stream);   // d_out poisoned 0xAA

    scatter_kernel<<<(NPAIR + 255) / 256, 256, 0, stream>>>(
        target, noise, cursor, buf);
    compute_kernel<<<NBIN, 256, 0, stream>>>(
        hidden, weight, bias, noise_probs, cursor, buf, out);
}

// Round 5
// 229.142 us; speedup vs baseline: 1.1817x; 1.1817x over previous
//
#include <hip/hip_runtime.h>
#include <math.h>

#define V 100000
#define D 256
#define B 32
#define N 128
#define K 100
#define NPOS (B * N)             // 4096
#define NPAIR (NPOS * (K + 1))   // 413,696
#define BIN_ROWS 32
#define NBIN (V / BIN_ROWS)      // 3125 (exact)
#define NSHARD 8
#define CAP_S 56                 // pairs per (bin,shard); mean 16.6, +~10 sigma
#define MAXTOT (NSHARD * CAP_S)  // 448 <= plist capacity 512
#define NORM_TERM 11.512925f
#define LOG_K 4.605170186f       // log(100)

typedef float f32x4 __attribute__((ext_vector_type(4)));

// softplus(x) = max(x,0) + log1p(exp(-|x|)) — overflow-safe, fast intrinsics
__device__ __forceinline__ float softplus(float x) {
    return fmaxf(x, 0.f) + __logf(1.f + __expf(-fabsf(x)));
}

// ---------- Pass 1: bin all (pos,row) pairs, 8-way sharded cursors ----------
// rec = (row%32)<<13 | pos<<1 | is_target
__global__ __launch_bounds__(256) void scatter_kernel(
    const int* __restrict__ target, const int* __restrict__ noise,
    int* __restrict__ cursor, unsigned* __restrict__ buf)
{
    const int p = blockIdx.x * 256 + threadIdx.x;
    if (p >= NPAIR) return;
    int row, pos; unsigned flag;
    if (p < NPOS * K) { pos = p / K; row = noise[p]; flag = 0u; }
    else              { pos = p - NPOS * K; row = target[pos]; flag = 1u; }
    const int bin   = row >> 5;                    // BIN_ROWS = 32
    const int shard = blockIdx.x & (NSHARD - 1);   // ~XCD-aligned
    const int cell  = bin * NSHARD + shard;
    const int slot  = atomicAdd(&cursor[cell], 1);
    if (slot < CAP_S)
        buf[(size_t)cell * CAP_S + slot] =
            ((unsigned)(row & (BIN_ROWS - 1)) << 13) | ((unsigned)pos << 1) | flag;
}

// ---------- Pass 2: one block per 32-row bin ----------
// Stream the bin's 32 KB fp32 weight slab into LDS (nontemporal, read-once),
// compact the 8 shard lists into LDS, then 16 lanes per pair: weight from
// LDS (fp32, no cvt), hidden from global (4 MB, L2-hot).
__global__ __launch_bounds__(256) void compute_kernel(
    const float* __restrict__ hidden, const float* __restrict__ weight,
    const float* __restrict__ bias, const float* __restrict__ noise_probs,
    const int* __restrict__ cursor, const unsigned* __restrict__ buf,
    float* __restrict__ out)
{
    __shared__ float    slab[BIN_ROWS * D];   // 32 KB fp32
    __shared__ float    sbias[BIN_ROWS];
    __shared__ float    slogp[BIN_ROWS];
    __shared__ unsigned plist[MAXTOT + 64];   // compacted pair records
    __shared__ int      pref[NSHARD + 1];
    __shared__ float    wsum[4];

    const int bin = blockIdx.x;
    const int tid = threadIdx.x;

    if (tid == 0) {
        int s = 0;
        #pragma unroll
        for (int i = 0; i < NSHARD; ++i) {
            pref[i] = s;
            s += min(cursor[bin * NSHARD + i], CAP_S);
        }
        pref[NSHARD] = s;
    }
    __syncthreads();
    const int total = pref[NSHARD];
    if (total == 0) return;                   // uniform exit

    const int wave = tid >> 6;                // 0..3
    const int lane = tid & 63;
    const int q    = lane >> 4;               // pair slot 0..3
    const int ql   = lane & 15;               // lane within quarter
    const int row0 = bin * BIN_ROWS;

    // stage slab: wave w loads rows w, w+4, ... — one 1 KB row per wave-instr
    for (int r = wave; r < BIN_ROWS; r += 4) {
        const f32x4 w4 = __builtin_nontemporal_load(
            (const f32x4*)(weight + (size_t)(row0 + r) * D + lane * 4));
        *(f32x4*)(slab + r * D + lane * 4) = w4;
    }
    if (tid < BIN_ROWS) {
        sbias[tid] = bias[row0 + tid];
        slogp[tid] = __logf(noise_probs[row0 + tid]);
    }
    // compact shard lists into plist
    for (int i = tid; i < total; i += 256) {
        int s = 0;
        #pragma unroll
        for (int j = 1; j < NSHARD; ++j) s += (i >= pref[j]);
        plist[i] = buf[((size_t)(bin * NSHARD + s)) * CAP_S + (i - pref[s])];
    }
    __syncthreads();

    float loss = 0.f;
    for (int base = wave * 4; base < total; base += 16) {
        const int p = base + q;
        const bool valid = (p < total);
        const unsigned rec = valid ? plist[p] : 0u;
        const int rloc = (int)((rec >> 13) & (BIN_ROWS - 1));
        const int pos  = (int)((rec >> 1) & (NPOS - 1));

        const float* __restrict__ hp = hidden + (size_t)pos * D + ql * 4;
        const float* __restrict__ wp = slab + rloc * D + ql * 4;
        float acc = 0.f;
        #pragma unroll
        for (int i = 0; i < 4; ++i) {
            const f32x4 h4 = *(const f32x4*)(hp + i * 64);
            const f32x4 w4 = *(const f32x4*)(wp + i * 64);
            acc = fmaf(w4.x, h4.x, acc);
            acc = fmaf(w4.y, h4.y, acc);
            acc = fmaf(w4.z, h4.z, acc);
            acc = fmaf(w4.w, h4.w, acc);
        }
        #pragma unroll
        for (int off = 1; off < 16; off <<= 1)    // reduce within quarter
            acc += __shfl_xor(acc, off, 64);

        const float score = acc + sbias[rloc] - NORM_TERM;
        const float contrib = (rec & 1u)
            ? softplus(LOG_K - score)                  // target, label 1
            : softplus(score - slogp[rloc] - LOG_K);   // noise, label 0
        if (valid && ql == 0) loss += contrib;
    }

    loss += __shfl_xor(loss, 16, 64);
    loss += __shfl_xor(loss, 32, 64);
    if (lane == 0) wsum[wave] = loss;
    __syncthreads();
    if (tid == 0)
        atomicAdd(out, (wsum[0] + wsum[1] + wsum[2] + wsum[3])
                       * (1.0f / (float)NPOS));
}

extern "C" void kernel_launch(void* const* d_in, const int* in_sizes, int n_in,
                              void* d_out, int out_size, void* d_ws, size_t ws_size,
                              hipStream_t stream) {
    const int*   target      = (const int*)d_in[0];
    const int*   noise       = (const int*)d_in[1];
    const float* hidden      = (const float*)d_in[2];
    const float* weight      = (const float*)d_in[3];
    const float* bias        = (const float*)d_in[4];
    const float* noise_probs = (const float*)d_in[5];
    float* out = (float*)d_out;

    // workspace: [0, 128K) sharded cursors, then pair records (~5.6 MB)
    int*      cursor = (int*)d_ws;
    unsigned* buf    = (unsigned*)((char*)d_ws + (size_t)NBIN * NSHARD * 4);

    hipMemsetAsync(cursor, 0, (size_t)NBIN * NSHARD * 4, stream);
    hipMemsetAsync(out, 0, sizeof(float), stream);   // d_out poisoned 0xAA

    scatter_kernel<<<(NPAIR + 255) / 256, 256, 0, stream>>>(
        target, noise, cursor, buf);
    compute_kernel<<<NBIN, 256, 0, stream>>>(
        hidden, weight, bias, noise_probs, cursor, buf, out);
}

// Round 6
// 226.587 us; speedup vs baseline: 1.1950x; 1.0113x over previous
//
#include <hip/hip_runtime.h>
#include <math.h>

#define V 100000
#define D 256
#define B 32
#define N 128
#define K 100
#define NPOS (B * N)             // 4096
#define NPAIR (NPOS * (K + 1))   // 413,696
#define BIN_ROWS 32
#define NBIN (V / BIN_ROWS)      // 3125 (exact)
#define NSHARD 8
#define CAP_S 56                 // pairs per (bin,shard); mean 16.6, +~10 sigma
#define MAXTOT (NSHARD * CAP_S)  // 448
#define SLAB_W (D + 8)           // u16 row stride: +8 pad spreads banks
#define NORM_TERM 11.512925f
#define LOG_K 4.605170186f       // log(100)

typedef float f32x4 __attribute__((ext_vector_type(4)));
typedef unsigned short u16;

// softplus(x) = max(x,0) + log1p(exp(-|x|)) — overflow-safe, fast intrinsics
__device__ __forceinline__ float softplus(float x) {
    return fmaxf(x, 0.f) + __logf(1.f + __expf(-fabsf(x)));
}
__device__ __forceinline__ unsigned f32_to_bf16_bits(float x) {  // RNE, in high16
    unsigned u = __float_as_uint(x);
    u += 0x7FFFu + ((u >> 16) & 1u);
    return u >> 16;
}

// ---------- Pass 1: bin all (pos,row) pairs, 8-way sharded cursors ----------
// rec = (row%32)<<13 | pos<<1 | is_target
__global__ __launch_bounds__(256) void scatter_kernel(
    const int* __restrict__ target, const int* __restrict__ noise,
    int* __restrict__ cursor, unsigned* __restrict__ buf)
{
    const int p = blockIdx.x * 256 + threadIdx.x;
    if (p >= NPAIR) return;
    int row, pos; unsigned flag;
    if (p < NPOS * K) { pos = p / K; row = noise[p]; flag = 0u; }
    else              { pos = p - NPOS * K; row = target[pos]; flag = 1u; }
    const int bin   = row >> 5;                    // BIN_ROWS = 32
    const int shard = blockIdx.x & (NSHARD - 1);
    const int cell  = bin * NSHARD + shard;
    const int slot  = atomicAdd(&cursor[cell], 1);
    if (slot < CAP_S)
        buf[(size_t)cell * CAP_S + slot] =
            ((unsigned)(row & (BIN_ROWS - 1)) << 13) | ((unsigned)pos << 1) | flag;
}

// ---------- Pass 2: one block per 32-row bin ----------
// bf16 slab (16.9 KB) + small LDS => 8 blocks/CU, launch_bounds(256,8) caps
// VGPR at 64 => 32 waves/CU for latency hiding. Weight streamed nontemporal
// (read-once); hidden gathered from global (4 MB, L2/LLC-hot).
__global__ __launch_bounds__(256, 8) void compute_kernel(
    const float* __restrict__ hidden, const float* __restrict__ weight,
    const float* __restrict__ bias, const float* __restrict__ noise_probs,
    const int* __restrict__ cursor, const unsigned* __restrict__ buf,
    float* __restrict__ out)
{
    __shared__ u16      slab[BIN_ROWS * SLAB_W];  // 16.9 KB bf16, padded rows
    __shared__ float    sbias[BIN_ROWS];
    __shared__ float    slogp[BIN_ROWS];
    __shared__ unsigned plist[MAXTOT];            // compacted pair records
    __shared__ int      scnt[NSHARD];
    __shared__ int      pref[NSHARD + 1];
    __shared__ float    wsum[4];

    const int bin = blockIdx.x;
    const int tid = threadIdx.x;

    if (tid < NSHARD)
        scnt[tid] = min(cursor[bin * NSHARD + tid], CAP_S);
    __syncthreads();
    if (tid == 0) {
        int s = 0;
        #pragma unroll
        for (int i = 0; i < NSHARD; ++i) { pref[i] = s; s += scnt[i]; }
        pref[NSHARD] = s;
    }
    __syncthreads();
    const int total = pref[NSHARD];
    if (total == 0) return;                       // uniform exit

    const int wave = tid >> 6;                    // 0..3
    const int lane = tid & 63;
    const int q    = lane >> 4;                   // pair slot 0..3
    const int ql   = lane & 15;                   // lane within quarter
    const int row0 = bin * BIN_ROWS;

    // stage slab: wave w rows w, w+4, ...: lane covers elems 4*lane..4*lane+3
    for (int r = wave; r < BIN_ROWS; r += 4) {
        const f32x4 w4 = __builtin_nontemporal_load(
            (const f32x4*)(weight + (size_t)(row0 + r) * D + lane * 4));
        uint2 b;
        b.x = f32_to_bf16_bits(w4.x) | (f32_to_bf16_bits(w4.y) << 16);
        b.y = f32_to_bf16_bits(w4.z) | (f32_to_bf16_bits(w4.w) << 16);
        *(uint2*)(slab + r * SLAB_W + lane * 4) = b;
    }
    if (tid < BIN_ROWS) {
        sbias[tid] = bias[row0 + tid];
        slogp[tid] = __logf(noise_probs[row0 + tid]);
    }
    // compact the 8 shard lists into plist
    for (int i = tid; i < total; i += 256) {
        int s = 0;
        #pragma unroll
        for (int j = 1; j < NSHARD; ++j) s += (i >= pref[j]);
        plist[i] = buf[((size_t)(bin * NSHARD + s)) * CAP_S + (i - pref[s])];
    }
    __syncthreads();

    float loss = 0.f;
    for (int base = wave * 4; base < total; base += 16) {
        const int p = base + q;
        const bool valid = (p < total);
        const unsigned rec = valid ? plist[p] : 0u;
        const int rloc = (int)((rec >> 13) & (BIN_ROWS - 1));
        const int pos  = (int)((rec >> 1) & (NPOS - 1));

        const float* __restrict__ hp = hidden + (size_t)pos * D + ql * 4;
        const u16*   __restrict__ wp = slab + rloc * SLAB_W + ql * 4;
        float acc = 0.f;
        #pragma unroll
        for (int i = 0; i < 4; ++i) {
            const f32x4 h4 = *(const f32x4*)(hp + i * 64);
            const uint2 wb = *(const uint2*)(wp + i * 64);
            acc = fmaf(__uint_as_float(wb.x << 16),          h4.x, acc);
            acc = fmaf(__uint_as_float(wb.x & 0xffff0000u),  h4.y, acc);
            acc = fmaf(__uint_as_float(wb.y << 16),          h4.z, acc);
            acc = fmaf(__uint_as_float(wb.y & 0xffff0000u),  h4.w, acc);
        }
        #pragma unroll
        for (int off = 1; off < 16; off <<= 1)    // reduce within quarter
            acc += __shfl_xor(acc, off, 64);

        const float score = acc + sbias[rloc] - NORM_TERM;
        const float contrib = (rec & 1u)
            ? softplus(LOG_K - score)                  // target, label 1
            : softplus(score - slogp[rloc] - LOG_K);   // noise, label 0
        if (valid && ql == 0) loss += contrib;
    }

    loss += __shfl_xor(loss, 16, 64);
    loss += __shfl_xor(loss, 32, 64);
    if (lane == 0) wsum[wave] = loss;
    __syncthreads();
    if (tid == 0)
        atomicAdd(out, (wsum[0] + wsum[1] + wsum[2] + wsum[3])
                       * (1.0f / (float)NPOS));
}

extern "C" void kernel_launch(void* const* d_in, const int* in_sizes, int n_in,
                              void* d_out, int out_size, void* d_ws, size_t ws_size,
                              hipStream_t stream) {
    const int*   target      = (const int*)d_in[0];
    const int*   noise       = (const int*)d_in[1];
    const float* hidden      = (const float*)d_in[2];
    const float* weight      = (const float*)d_in[3];
    const float* bias        = (const float*)d_in[4];
    const float* noise_probs = (const float*)d_in[5];
    float* out = (float*)d_out;

    // workspace: [0, 100K) sharded cursors, then pair records (~5.6 MB)
    int*      cursor = (int*)d_ws;
    unsigned* buf    = (unsigned*)((char*)d_ws + (size_t)NBIN * NSHARD * 4);

    hipMemsetAsync(cursor, 0, (size_t)NBIN * NSHARD * 4, stream);
    hipMemsetAsync(out, 0, sizeof(float), stream);   // d_out poisoned 0xAA

    scatter_kernel<<<(NPAIR + 255) / 256, 256, 0, stream>>>(
        target, noise, cursor, buf);
    compute_kernel<<<NBIN, 256, 0, stream>>>(
        hidden, weight, bias, noise_probs, cursor, buf, out);
}

// Round 7
// 223.693 us; speedup vs baseline: 1.2104x; 1.0129x over previous
//
#include <hip/hip_runtime.h>
#include <math.h>

#define V 100000
#define D 256
#define B 32
#define N 128
#define K 100
#define NPOS (B * N)             // 4096
#define NPAIR (NPOS * (K + 1))   // 413,696
#define BIN_ROWS 32
#define NBIN (V / BIN_ROWS)      // 3125 (exact)
#define NSHARD 16
#define CAP_S 32                 // pairs per (bin,shard); mean 8.3, +8 sigma
#define MAXTOT (NSHARD * CAP_S)  // 512
#define SLAB_W (D + 8)           // u16 row stride: +8 pad spreads banks
#define NORM_TERM 11.512925f
#define LOG_K 4.605170186f       // log(100)

typedef float f32x4 __attribute__((ext_vector_type(4)));
typedef unsigned short u16;

// softplus(x) = max(x,0) + log1p(exp(-|x|)) — overflow-safe, fast intrinsics
__device__ __forceinline__ float softplus(float x) {
    return fmaxf(x, 0.f) + __logf(1.f + __expf(-fabsf(x)));
}
__device__ __forceinline__ unsigned f32_to_bf16_bits(float x) {  // RNE
    unsigned u = __float_as_uint(x);
    u += 0x7FFFu + ((u >> 16) & 1u);
    return u >> 16;
}

// Pure-VALU 16-lane butterfly sum via DPP involutions (no LDS pipe):
// quad_perm [1,0,3,2] (xor1), quad_perm [2,3,0,1] (xor2),
// row_half_mirror (pairs quads within 8), row_mirror (pairs 8-groups).
// All 16 lanes of each quarter end up with the full sum.
template <int CTRL>
__device__ __forceinline__ float dpp_add(float x) {
    int y = __builtin_amdgcn_update_dpp(__float_as_int(x), __float_as_int(x),
                                        CTRL, 0xF, 0xF, false);
    return x + __int_as_float(y);
}
__device__ __forceinline__ float quarter_sum(float x) {
    x = dpp_add<0xB1>(x);    // quad_perm [1,0,3,2]
    x = dpp_add<0x4E>(x);    // quad_perm [2,3,0,1]
    x = dpp_add<0x141>(x);   // row_half_mirror
    x = dpp_add<0x140>(x);   // row_mirror
    return x;
}

// ---------- Pass 1: bin all (pos,row) pairs, 16-way sharded cursors ----------
// rec = (row%32)<<13 | pos<<1 | is_target
__global__ __launch_bounds__(256) void scatter_kernel(
    const int* __restrict__ target, const int* __restrict__ noise,
    int* __restrict__ cursor, unsigned* __restrict__ buf)
{
    const int p = blockIdx.x * 256 + threadIdx.x;
    if (p >= NPAIR) return;
    int row, pos; unsigned flag;
    if (p < NPOS * K) { pos = p / K; row = noise[p]; flag = 0u; }
    else              { pos = p - NPOS * K; row = target[pos]; flag = 1u; }
    const int bin   = row >> 5;                    // BIN_ROWS = 32
    const int shard = blockIdx.x & (NSHARD - 1);
    const int cell  = bin * NSHARD + shard;
    const int slot  = atomicAdd(&cursor[cell], 1);
    if (slot < CAP_S)
        buf[(size_t)cell * CAP_S + slot] =
            ((unsigned)(row & (BIN_ROWS - 1)) << 13) | ((unsigned)pos << 1) | flag;
}

// ---------- Pass 2: one block per 32-row bin, software-pipelined ----------
__global__ __launch_bounds__(256, 6) void compute_kernel(
    const float* __restrict__ hidden, const float* __restrict__ weight,
    const float* __restrict__ bias, const float* __restrict__ noise_probs,
    const int* __restrict__ cursor, const unsigned* __restrict__ buf,
    float* __restrict__ out)
{
    __shared__ u16      slab[BIN_ROWS * SLAB_W];  // 16.9 KB bf16, padded rows
    __shared__ float    sbias[BIN_ROWS];
    __shared__ float    slogp[BIN_ROWS];
    __shared__ unsigned plist[MAXTOT];
    __shared__ int      scnt[NSHARD];
    __shared__ int      pref[NSHARD + 1];
    __shared__ float    wsum[4];

    const int bin = blockIdx.x;
    const int tid = threadIdx.x;

    if (tid < NSHARD)
        scnt[tid] = min(cursor[bin * NSHARD + tid], CAP_S);
    __syncthreads();
    if (tid == 0) {
        int s = 0;
        #pragma unroll
        for (int i = 0; i < NSHARD; ++i) { pref[i] = s; s += scnt[i]; }
        pref[NSHARD] = s;
    }
    __syncthreads();
    const int total = pref[NSHARD];
    if (total == 0) return;                       // uniform exit

    const int wave = tid >> 6;                    // 0..3
    const int lane = tid & 63;
    const int q    = lane >> 4;                   // pair slot 0..3
    const int ql   = lane & 15;                   // lane within quarter
    const int row0 = bin * BIN_ROWS;

    // stage slab: wave w rows w, w+4, ... — one 1 KB row per wave-instr
    for (int r = wave; r < BIN_ROWS; r += 4) {
        const f32x4 w4 = __builtin_nontemporal_load(
            (const f32x4*)(weight + (size_t)(row0 + r) * D + lane * 4));
        uint2 b;
        b.x = f32_to_bf16_bits(w4.x) | (f32_to_bf16_bits(w4.y) << 16);
        b.y = f32_to_bf16_bits(w4.z) | (f32_to_bf16_bits(w4.w) << 16);
        *(uint2*)(slab + r * SLAB_W + lane * 4) = b;
    }
    if (tid < BIN_ROWS) {
        sbias[tid] = bias[row0 + tid];
        slogp[tid] = __logf(noise_probs[row0 + tid]);
    }
    // compact the 16 shard lists into plist
    for (int i = tid; i < total; i += 256) {
        int s = 0;
        #pragma unroll
        for (int j = 1; j < NSHARD; ++j) s += (i >= pref[j]);
        plist[i] = buf[((size_t)(bin * NSHARD + s)) * CAP_S + (i - pref[s])];
    }
    __syncthreads();

    // ---- software-pipelined pass loop: 2-deep rec, 1-deep operand prefetch
    const int p0 = wave * 4 + q;

    unsigned rec_c  = (p0      < total) ? plist[p0]      : 0u;
    unsigned rec_nx = (p0 + 16 < total) ? plist[p0 + 16] : 0u;

    f32x4 hc[4], hn[4];
    uint2 wc[4], wn[4];

    {   // issue operand loads for rec_c and rec_nx
        const float* hp = hidden + (size_t)((rec_c >> 1) & (NPOS - 1)) * D + ql * 4;
        const u16*   wp = slab + ((rec_c >> 13) & (BIN_ROWS - 1)) * SLAB_W + ql * 4;
        #pragma unroll
        for (int i = 0; i < 4; ++i) {
            hc[i] = *(const f32x4*)(hp + i * 64);
            wc[i] = *(const uint2*)(wp + i * 64);
        }
        const float* hp2 = hidden + (size_t)((rec_nx >> 1) & (NPOS - 1)) * D + ql * 4;
        const u16*   wp2 = slab + ((rec_nx >> 13) & (BIN_ROWS - 1)) * SLAB_W + ql * 4;
        #pragma unroll
        for (int i = 0; i < 4; ++i) {
            hn[i] = *(const f32x4*)(hp2 + i * 64);
            wn[i] = *(const uint2*)(wp2 + i * 64);
        }
    }

    float loss = 0.f;
    for (int base = wave * 4; base < total; base += 16) {
        const int p = base + q;
        // prefetch rec for p+32 (LDS latency overlapped with compute below)
        const unsigned rec_2 = (p + 32 < total) ? plist[p + 32] : 0u;

        // ---- compute pair p from pipelined operands (rec_c, hc, wc)
        float s0 = 0.f, s1 = 0.f, s2 = 0.f, s3 = 0.f;
        s0 = fmaf(__uint_as_float(wc[0].x << 16),         hc[0].x, s0);
        s0 = fmaf(__uint_as_float(wc[0].x & 0xffff0000u), hc[0].y, s0);
        s0 = fmaf(__uint_as_float(wc[0].y << 16),         hc[0].z, s0);
        s0 = fmaf(__uint_as_float(wc[0].y & 0xffff0000u), hc[0].w, s0);
        s1 = fmaf(__uint_as_float(wc[1].x << 16),         hc[1].x, s1);
        s1 = fmaf(__uint_as_float(wc[1].x & 0xffff0000u), hc[1].y, s1);
        s1 = fmaf(__uint_as_float(wc[1].y << 16),         hc[1].z, s1);
        s1 = fmaf(__uint_as_float(wc[1].y & 0xffff0000u), hc[1].w, s1);
        s2 = fmaf(__uint_as_float(wc[2].x << 16),         hc[2].x, s2);
        s2 = fmaf(__uint_as_float(wc[2].x & 0xffff0000u), hc[2].y, s2);
        s2 = fmaf(__uint_as_float(wc[2].y << 16),         hc[2].z, s2);
        s2 = fmaf(__uint_as_float(wc[2].y & 0xffff0000u), hc[2].w, s2);
        s3 = fmaf(__uint_as_float(wc[3].x << 16),         hc[3].x, s3);
        s3 = fmaf(__uint_as_float(wc[3].x & 0xffff0000u), hc[3].y, s3);
        s3 = fmaf(__uint_as_float(wc[3].y << 16),         hc[3].z, s3);
        s3 = fmaf(__uint_as_float(wc[3].y & 0xffff0000u), hc[3].w, s3);

        const float r = quarter_sum((s0 + s1) + (s2 + s3));  // all 16 lanes

        const int rloc = (int)((rec_c >> 13) & (BIN_ROWS - 1));
        const float score = r + sbias[rloc] - NORM_TERM;
        const float x = (rec_c & 1u) ? (LOG_K - score)
                                     : (score - slogp[rloc] - LOG_K);
        if ((p < total) && ql == 0) loss += softplus(x);

        // ---- rotate pipeline and issue loads for p+32
        rec_c  = rec_nx;
        rec_nx = rec_2;
        #pragma unroll
        for (int i = 0; i < 4; ++i) { hc[i] = hn[i]; wc[i] = wn[i]; }
        const float* hp = hidden + (size_t)((rec_nx >> 1) & (NPOS - 1)) * D + ql * 4;
        const u16*   wp = slab + ((rec_nx >> 13) & (BIN_ROWS - 1)) * SLAB_W + ql * 4;
        #pragma unroll
        for (int i = 0; i < 4; ++i) {
            hn[i] = *(const f32x4*)(hp + i * 64);
            wn[i] = *(const uint2*)(wp + i * 64);
        }
    }

    // fold quarters (loss lives on ql==0 lanes: 0,16,32,48), then waves
    loss += __shfl_xor(loss, 16, 64);
    loss += __shfl_xor(loss, 32, 64);
    if (lane == 0) wsum[wave] = loss;
    __syncthreads();
    if (tid == 0)
        atomicAdd(out, (wsum[0] + wsum[1] + wsum[2] + wsum[3])
                       * (1.0f / (float)NPOS));
}

extern "C" void kernel_launch(void* const* d_in, const int* in_sizes, int n_in,
                              void* d_out, int out_size, void* d_ws, size_t ws_size,
                              hipStream_t stream) {
    const int*   target      = (const int*)d_in[0];
    const int*   noise       = (const int*)d_in[1];
    const float* hidden      = (const float*)d_in[2];
    const float* weight      = (const float*)d_in[3];
    const float* bias        = (const float*)d_in[4];
    const float* noise_probs = (const float*)d_in[5];
    float* out = (float*)d_out;

    // workspace: [0, 200K) sharded cursors, then pair records (~6.4 MB)
    int*      cursor = (int*)d_ws;
    unsigned* buf    = (unsigned*)((char*)d_ws + (size_t)NBIN * NSHARD * 4);

    hipMemsetAsync(cursor, 0, (size_t)NBIN * NSHARD * 4, stream);
    hipMemsetAsync(out, 0, sizeof(float), stream);   // d_out poisoned 0xAA

    scatter_kernel<<<(NPAIR + 255) / 256, 256, 0, stream>>>(
        target, noise, cursor, buf);
    compute_kernel<<<NBIN, 256, 0, stream>>>(
        hidden, weight, bias, noise_probs, cursor, buf, out);
}